// Round 6
// baseline (347.866 us; speedup 1.0000x reference)
//
#include <hip/hip_runtime.h>

#define SEQ 1024
#define BATCH 512
#define NTAGS 64
#define HALF_T 512
#define LOGD 4.158883083f   // log(64): per-step damp folded into exp(em)

typedef _Float16 v2h __attribute__((ext_vector_type(2)));

__device__ __forceinline__ float dot2acc(v2h a, v2h b, float c) {
#if __has_builtin(__builtin_amdgcn_fdot2)
    return __builtin_amdgcn_fdot2(a, b, c, false);
#else
    return fmaf((float)a.x, (float)b.x, fmaf((float)a.y, (float)b.y, c));
#endif
}

__device__ __forceinline__ float rfl(float x) {
    return __uint_as_float(__builtin_amdgcn_readfirstlane(__float_as_uint(x)));
}

__device__ __forceinline__ v2h bcv(unsigned x) { return __builtin_bit_cast(v2h, x); }

template<int CTRL>
__device__ __forceinline__ unsigned dppmov(unsigned v) {
    return (unsigned)__builtin_amdgcn_mov_dpp((int)v, CTRL, 0xf, 0xf, false);
}

// Pair across the 32-lane boundary: {a,b} hold {x_l, x_{l^32}} in a
// lane-dependent order; order irrelevant (index-mirrored weight layout).
__device__ __forceinline__ void swap32pair(unsigned x, unsigned& a, unsigned& b) {
#if __has_builtin(__builtin_amdgcn_permlane32_swap)
    auto r = __builtin_amdgcn_permlane32_swap(x, x, false, false);
    a = (unsigned)r[0]; b = (unsigned)r[1];
#else
    a = x; b = (unsigned)__shfl_xor((int)x, 32);
#endif
}

__device__ __forceinline__ void swap16pair(unsigned x, unsigned& a, unsigned& b) {
#if __has_builtin(__builtin_amdgcn_permlane16_swap)
    auto r = __builtin_amdgcn_permlane16_swap(x, x, false, false);
    a = (unsigned)r[0]; b = (unsigned)r[1];
#else
    a = x; b = (unsigned)__shfl_xor((int)x, 16);
#endif
}

__device__ __forceinline__ unsigned pkrtz(float lo, float hi) {
#if __has_builtin(__builtin_amdgcn_cvt_pkrtz)
    auto p = __builtin_amdgcn_cvt_pkrtz(lo, hi);
    return __builtin_bit_cast(unsigned, p);
#else
    v2h t; t.x = (_Float16)lo; t.y = (_Float16)hi;
    return __builtin_bit_cast(unsigned, t);
#endif
}

// Doubling butterfly, FULLY SCALAR (R5 post-mortem: array-parameter
// versions of this routine put u[]/p[] in scratch -> ~720 cyc/step of
// stall; scalars + references are mem2reg-trivial).
// Levels: 16-swap, 0x140, 0x141, quad_perm 0x4E, quad_perm 0xB1.
// Semantics identical to the array expand64 (verified absmax=0 in R4/R5).
__device__ __forceinline__ void expand64s(unsigned p0,
    unsigned& u0,  unsigned& u1,  unsigned& u2,  unsigned& u3,
    unsigned& u4,  unsigned& u5,  unsigned& u6,  unsigned& u7,
    unsigned& u8,  unsigned& u9,  unsigned& u10, unsigned& u11,
    unsigned& u12, unsigned& u13, unsigned& u14, unsigned& u15,
    unsigned& u16, unsigned& u17, unsigned& u18, unsigned& u19,
    unsigned& u20, unsigned& u21, unsigned& u22, unsigned& u23,
    unsigned& u24, unsigned& u25, unsigned& u26, unsigned& u27,
    unsigned& u28, unsigned& u29, unsigned& u30, unsigned& u31)
{
    swap16pair(p0, u0, u1);
    u2  = dppmov<0x140>(u0);  u3  = dppmov<0x140>(u1);
    u4  = dppmov<0x141>(u0);  u5  = dppmov<0x141>(u1);
    u6  = dppmov<0x141>(u2);  u7  = dppmov<0x141>(u3);
    u8  = dppmov<0x4E>(u0);   u9  = dppmov<0x4E>(u1);
    u10 = dppmov<0x4E>(u2);   u11 = dppmov<0x4E>(u3);
    u12 = dppmov<0x4E>(u4);   u13 = dppmov<0x4E>(u5);
    u14 = dppmov<0x4E>(u6);   u15 = dppmov<0x4E>(u7);
    u16 = dppmov<0xB1>(u0);   u17 = dppmov<0xB1>(u1);
    u18 = dppmov<0xB1>(u2);   u19 = dppmov<0xB1>(u3);
    u20 = dppmov<0xB1>(u4);   u21 = dppmov<0xB1>(u5);
    u22 = dppmov<0xB1>(u6);   u23 = dppmov<0xB1>(u7);
    u24 = dppmov<0xB1>(u8);   u25 = dppmov<0xB1>(u9);
    u26 = dppmov<0xB1>(u10);  u27 = dppmov<0xB1>(u11);
    u28 = dppmov<0xB1>(u12);  u29 = dppmov<0xB1>(u13);
    u30 = dppmov<0xB1>(u14);  u31 = dppmov<0xB1>(u15);
}

// Fused CRF kernel: block b runs BOTH chains of batch b.
//   wave0 (fwd): t = 1..min(L-1,511);  wave1 (bwd): t = L-1..512 descending.
// Per-step 64-wide broadcast = pure-VALU butterfly (permlane+DPP), no LDS,
// no scratch (all scalars). Weight layout matches butterfly delivery order
// via the index butterfly at init.
__global__ __launch_bounds__(128, 1)
void crf_kernel(const float* __restrict__ em,
                const int* __restrict__ tags,
                const int* __restrict__ mask,
                const float* __restrict__ startT,
                const float* __restrict__ endT,
                const float* __restrict__ trans,
                float* __restrict__ out)
{
    const int  b   = blockIdx.x;
    const int  wid = threadIdx.x >> 6;
    const int  j   = threadIdx.x & 63;
    const bool fwd = (wid == 0);

    __shared__ float gsh[NTAGS];   // gamma from bwd wave
    __shared__ float mb_np[2];     // [0]=Mb, [1]=np partial (bwd)

    // chain length = sum of this batch's mask column
    int lsum = 0;
#pragma unroll
    for (int k = 0; k < SEQ / 64; ++k)
        lsum += mask[(k * 64 + j) * BATCH + b];
#pragma unroll
    for (int off = 32; off > 0; off >>= 1)
        lsum += __shfl_xor(lsum, off);
    const int L = lsum;

    // Index butterfly: which beta-index lands in each slot/component.
    unsigned I0,I1,I2,I3,I4,I5,I6,I7,I8,I9,I10,I11,I12,I13,I14,I15,
             I16,I17,I18,I19,I20,I21,I22,I23,I24,I25,I26,I27,I28,I29,I30,I31;
    {
        unsigned ia_, ib_;
        swap32pair((unsigned)j, ia_, ib_);
        unsigned iseed = (ia_ & 0xffffu) | (ib_ << 16);
        expand64s(iseed, I0,I1,I2,I3,I4,I5,I6,I7,I8,I9,I10,I11,I12,I13,I14,I15,
                  I16,I17,I18,I19,I20,I21,I22,I23,I24,I25,I26,I27,I28,I29,I30,I31);
    }

    // fp16 expT fragment matched to butterfly delivery order:
    // fwd lane j = column j (T[i][j]); bwd lane j = row j (T[j][i]).
    v2h w0,w1,w2,w3,w4,w5,w6,w7,w8,w9,w10,w11,w12,w13,w14,w15,
        w16,w17,w18,w19,w20,w21,w22,w23,w24,w25,w26,w27,w28,w29,w30,w31;
#define WINIT(S)                                                               \
    {                                                                          \
        unsigned i0_ = I##S & 0xffffu, i1_ = I##S >> 16;                       \
        float a0_ = fwd ? trans[i0_ * NTAGS + j] : trans[j * NTAGS + i0_];     \
        float a1_ = fwd ? trans[i1_ * NTAGS + j] : trans[j * NTAGS + i1_];     \
        w##S.x = (_Float16)__expf(a0_); w##S.y = (_Float16)__expf(a1_);        \
    }
    WINIT(0)  WINIT(1)  WINIT(2)  WINIT(3)  WINIT(4)  WINIT(5)  WINIT(6)  WINIT(7)
    WINIT(8)  WINIT(9)  WINIT(10) WINIT(11) WINIT(12) WINIT(13) WINIT(14) WINIT(15)
    WINIT(16) WINIT(17) WINIT(18) WINIT(19) WINIT(20) WINIT(21) WINIT(22) WINIT(23)
    WINIT(24) WINIT(25) WINIT(26) WINIT(27) WINIT(28) WINIT(29) WINIT(30) WINIT(31)
#undef WINIT

// Broadcast beta -> 32 packed-fp16 regs (all scalars), then 32 fdot2 into
// 8 accumulators. Pairing u_s <-> w_s, accumulator s&7 (same as R4 array
// version: s = 8q+r pairs into accum r).
#define DOT(WRVAL, SOUT)                                                       \
    {                                                                          \
        unsigned ba_, bb_;                                                     \
        swap32pair(__float_as_uint(WRVAL), ba_, bb_);                          \
        unsigned pk_ = pkrtz(__uint_as_float(ba_), __uint_as_float(bb_));      \
        unsigned u0_,u1_,u2_,u3_,u4_,u5_,u6_,u7_,u8_,u9_,u10_,u11_,u12_,u13_,  \
                 u14_,u15_,u16_,u17_,u18_,u19_,u20_,u21_,u22_,u23_,u24_,u25_,  \
                 u26_,u27_,u28_,u29_,u30_,u31_;                                \
        expand64s(pk_, u0_,u1_,u2_,u3_,u4_,u5_,u6_,u7_,u8_,u9_,u10_,u11_,      \
                  u12_,u13_,u14_,u15_,u16_,u17_,u18_,u19_,u20_,u21_,u22_,      \
                  u23_,u24_,u25_,u26_,u27_,u28_,u29_,u30_,u31_);               \
        float s0_=0.f,s1_=0.f,s2_=0.f,s3_=0.f,s4_=0.f,s5_=0.f,s6_=0.f,s7_=0.f; \
        s0_ = dot2acc(bcv(u0_),  w0,  s0_);                                    \
        s1_ = dot2acc(bcv(u1_),  w1,  s1_);                                    \
        s2_ = dot2acc(bcv(u2_),  w2,  s2_);                                    \
        s3_ = dot2acc(bcv(u3_),  w3,  s3_);                                    \
        s4_ = dot2acc(bcv(u4_),  w4,  s4_);                                    \
        s5_ = dot2acc(bcv(u5_),  w5,  s5_);                                    \
        s6_ = dot2acc(bcv(u6_),  w6,  s6_);                                    \
        s7_ = dot2acc(bcv(u7_),  w7,  s7_);                                    \
        s0_ = dot2acc(bcv(u8_),  w8,  s0_);                                    \
        s1_ = dot2acc(bcv(u9_),  w9,  s1_);                                    \
        s2_ = dot2acc(bcv(u10_), w10, s2_);                                    \
        s3_ = dot2acc(bcv(u11_), w11, s3_);                                    \
        s4_ = dot2acc(bcv(u12_), w12, s4_);                                    \
        s5_ = dot2acc(bcv(u13_), w13, s5_);                                    \
        s6_ = dot2acc(bcv(u14_), w14, s6_);                                    \
        s7_ = dot2acc(bcv(u15_), w15, s7_);                                    \
        s0_ = dot2acc(bcv(u16_), w16, s0_);                                    \
        s1_ = dot2acc(bcv(u17_), w17, s1_);                                    \
        s2_ = dot2acc(bcv(u18_), w18, s2_);                                    \
        s3_ = dot2acc(bcv(u19_), w19, s3_);                                    \
        s4_ = dot2acc(bcv(u20_), w20, s4_);                                    \
        s5_ = dot2acc(bcv(u21_), w21, s5_);                                    \
        s6_ = dot2acc(bcv(u22_), w22, s6_);                                    \
        s7_ = dot2acc(bcv(u23_), w23, s7_);                                    \
        s0_ = dot2acc(bcv(u24_), w24, s0_);                                    \
        s1_ = dot2acc(bcv(u25_), w25, s1_);                                    \
        s2_ = dot2acc(bcv(u26_), w26, s2_);                                    \
        s3_ = dot2acc(bcv(u27_), w27, s3_);                                    \
        s4_ = dot2acc(bcv(u28_), w28, s4_);                                    \
        s5_ = dot2acc(bcv(u29_), w29, s5_);                                    \
        s6_ = dot2acc(bcv(u30_), w30, s6_);                                    \
        s7_ = dot2acc(bcv(u31_), w31, s7_);                                    \
        SOUT = ((s0_ + s1_) + (s2_ + s3_)) + ((s4_ + s5_) + (s6_ + s7_));      \
    }

    float beta, M;
    int nsteps = 0;

    if (fwd) {
        float em0 = em[(size_t)b * NTAGS + j];
        float a0  = startT[j] + em0;
        M    = __shfl(a0, 0);
        beta = __expf(a0 - M);

        const int Lf = min(L - 1, HALF_T - 1);   // active steps t=1..Lf
        int t = 1;
        float cur[4], nxt[4];
#pragma unroll
        for (int u = 0; u < 4; ++u) {
            cur[u] = em[((size_t)min(t + u,     SEQ - 1) * BATCH + b) * NTAGS + j];
            nxt[u] = em[((size_t)min(t + 4 + u, SEQ - 1) * BATCH + b) * NTAGS + j];
        }
        while (t + 3 <= Lf) {
            float pre[4];
#pragma unroll
            for (int u = 0; u < 4; ++u)
                pre[u] = em[((size_t)min(t + 8 + u, SEQ - 1) * BATCH + b) * NTAGS + j];
            float eem[4];
#pragma unroll
            for (int u = 0; u < 4; ++u) eem[u] = __expf(cur[u] - LOGD);

            float s;
            DOT(beta, s); beta = s * eem[0];
            DOT(beta, s);
            float r = rfl(s);                 // uniform-ish positive renorm scale
            beta = s * eem[1];
            DOT(beta, s); beta = s * eem[2];
            float rinv = 1.0f / r;            // off-path
            float lr   = __logf(r);           // off-path
            DOT(beta, s); beta = s * (eem[3] * rinv);
            M += lr;
            nsteps += 4;
#pragma unroll
            for (int u = 0; u < 4; ++u) { cur[u] = nxt[u]; nxt[u] = pre[u]; }
            t += 4;
        }
        for (; t <= Lf; ++t) {
            float emt = em[((size_t)t * BATCH + b) * NTAGS + j];
            float s; DOT(beta, s);
            beta = s * __expf(emt - LOGD);
            ++nsteps;
        }
    } else {
        beta = __expf(endT[j]);               // B_j init (frozen for t >= L)
        M = 0.0f;
        if (L - 1 >= HALF_T) {
            int tt = L - 1;                   // steps tt = L-1 .. 512 descending
            float cur[4], nxt[4];
#pragma unroll
            for (int u = 0; u < 4; ++u) {
                cur[u] = em[((size_t)max(tt - u,     0) * BATCH + b) * NTAGS + j];
                nxt[u] = em[((size_t)max(tt - 4 - u, 0) * BATCH + b) * NTAGS + j];
            }
            while (tt - 3 >= HALF_T) {
                float pre[4];
#pragma unroll
                for (int u = 0; u < 4; ++u)
                    pre[u] = em[((size_t)max(tt - 8 - u, 0) * BATCH + b) * NTAGS + j];
                float eem[4];
#pragma unroll
                for (int u = 0; u < 4; ++u) eem[u] = __expf(cur[u] - LOGD);

                float s;
                DOT(beta * eem[0], s); beta = s;
                DOT(beta * eem[1], s);
                float r = rfl(s);
                beta = s;
                DOT(beta * eem[2], s); beta = s;
                float rinv = 1.0f / r;
                float lr   = __logf(r);
                DOT(beta * (eem[3] * rinv), s); beta = s;
                M += lr;
                nsteps += 4;
#pragma unroll
                for (int u = 0; u < 4; ++u) { cur[u] = nxt[u]; nxt[u] = pre[u]; }
                tt -= 4;
            }
            for (; tt >= HALF_T; --tt) {
                float emt = em[((size_t)tt * BATCH + b) * NTAGS + j];
                float s; DOT(beta * __expf(emt - LOGD), s);
                beta = s;
                ++nsteps;
            }
        }
    }
#undef DOT

    const float Mfb = fmaf((float)nsteps, LOGD, M);  // per-wave log-scale

    if (!fwd) {
        gsh[j] = beta;                      // gamma vector
        if (j == 0) mb_np[0] = Mfb;         // Mb
    }

    // numerator partial: thread tid handles t = k*128 + tid
    float np = 0.0f;
#pragma unroll
    for (int k = 0; k < SEQ / 128; ++k) {
        int t = k * 128 + wid * 64 + j;
        if (t >= 1 && t < L) {
            int ct = tags[t * BATCH + b];
            int pt = tags[(t - 1) * BATCH + b];
            np += trans[pt * NTAGS + ct] + em[((size_t)t * BATCH + b) * NTAGS + ct];
        }
    }
    if (threadIdx.x == 0) {
        int t0 = tags[b];
        np += startT[t0] + em[(size_t)b * NTAGS + t0]
            + endT[tags[(size_t)(L - 1) * BATCH + b]];
    }
#pragma unroll
    for (int off = 32; off > 0; off >>= 1)
        np += __shfl_xor(np, off);
    if (!fwd && j == 0) mb_np[1] = np;

    __syncthreads();

    if (fwd) {
        float p = beta * gsh[j];            // midpoint dot: beta_f . gamma
#pragma unroll
        for (int off = 32; off > 0; off >>= 1)
            p += __shfl_xor(p, off);
        if (j == 0) {
            float denom = __logf(p) + Mfb + mb_np[0];
            atomicAdd(out, (np + mb_np[1]) - denom);
        }
    }
}

extern "C" void kernel_launch(void* const* d_in, const int* in_sizes, int n_in,
                              void* d_out, int out_size, void* d_ws, size_t ws_size,
                              hipStream_t stream)
{
    const float* em     = (const float*)d_in[0];
    const int*   tags   = (const int*)d_in[1];
    const int*   mask   = (const int*)d_in[2];
    const float* startT = (const float*)d_in[3];
    const float* endT   = (const float*)d_in[4];
    const float* trans  = (const float*)d_in[5];
    float*       out    = (float*)d_out;

    (void)d_ws; (void)ws_size;

    hipMemsetAsync(out, 0, sizeof(float) * out_size, stream);
    crf_kernel<<<BATCH, 128, 0, stream>>>(em, tags, mask, startT, endT, trans, out);
}